// Round 1
// baseline (79.453 us; speedup 1.0000x reference)
//
#include <hip/hip_runtime.h>
#include <math.h>

#define K_COMP 128
#define LOG2E 1.4426950408889634f
#define INV_SQRT_2PI 0.3989422804014327f
#define PPT 8           // points per thread (was 16): lower VGPR, more blocks
#define BLOCK 256
#define REP 32          // scalar replicas per row (one per bank)

// prob[n] = sum_k exp2( -(s*(x-mu_k))^2 + lc_k ),  s = sqrt(0.5*exp(-lv)*log2e) uniform,
// lc_k = log2( softmax(pi)_k * inv_sqrt_2pi * exp(-lv_k/2) ).
// Runtime-selected paths (checks derived from ACTUAL params, never assumed):
//   win=3: uniform A AND uniform lc, 8-window safe -> gather scaled-mu only,
//          8 ds_read_b32/pt, t = fma(sd, -sd, lc_uniform)   [hot path]
//   win=2: uniform A, 8-window safe, nonuniform lc -> lc gathered from sRaw (cold)
//   win=1: uniform A, 12-window safe (2^-30 cutoff) (cold)
//   win=0: full 128-component loop (always correct, cold)
// smu bank-replicated: s[k*32 + (lane&31)] -> bank = lane&31 always, 2-way alias free.
// LDS total 18.4 KB -> 8 blocks/CU -> 32 waves/CU (was 34.8 KB / 16 waves).

template <int W, int OFF, bool UNIF_LC>
__device__ __forceinline__ void eval_win(const float* __restrict__ smu,
                                         const float* __restrict__ lcz,
                                         int lrep, float sscl, float lc_u,
                                         const float* x, float* acc) {
    #pragma unroll
    for (int p = 0; p < PPT; p++) {
        float xp = x[p];
        int k0 = min(max((int)(xp * 127.0f) - OFF, 0), K_COMP - W);
        const float* mrow = &smu[(k0 << 5) + lrep];
        float sx = xp * sscl;
        float a0 = 0.0f, a1 = 0.0f;
        if (UNIF_LC) {
            float mv[W];
            #pragma unroll
            for (int j = 0; j < W; j++)
                mv[j] = mrow[j << 5];            // ds_read_b32, imm offset j*128B
            #pragma unroll
            for (int j = 0; j < W; j += 2) {
                float sd0 = sx - mv[j];
                a0 += __builtin_amdgcn_exp2f(__builtin_fmaf(sd0, -sd0, lc_u));
                float sd1 = sx - mv[j + 1];
                a1 += __builtin_amdgcn_exp2f(__builtin_fmaf(sd1, -sd1, lc_u));
            }
        } else {
            // cold path: lc gathered from sRaw[k].z (stride 16B; conflicts OK here)
            const float* crow = lcz + ((long)k0 << 2);
            #pragma unroll
            for (int j = 0; j < W; j++) {
                float mvj = mrow[j << 5];
                float lcj = crow[j << 2];
                float sd = sx - mvj;
                float e = __builtin_amdgcn_exp2f(__builtin_fmaf(sd, -sd, lcj));
                if (j & 1) a1 += e; else a0 += e;
            }
        }
        acc[p] = a0 + a1;
    }
}

__global__ __launch_bounds__(BLOCK, 8) void gmm_fused(const float* __restrict__ mz,
                                                      const float* __restrict__ pi_l,
                                                      const float* __restrict__ mu,
                                                      const float* __restrict__ lv,
                                                      float* __restrict__ out,
                                                      int n) {
    __shared__ float smu[K_COMP * REP];   // 16 KB: replicated s*mu
    __shared__ float4 sRaw[K_COMP];       // 2 KB: {s*mu, A, lc, mu} per component
    __shared__ float sLC, sS;
    __shared__ int sWin;

    int tid = threadIdx.x;

    // ---- hoisted global loads: in flight while phase 1/2 run ----
    const float4* mz4 = (const float4*)mz;
    long base4 = (long)blockIdx.x * (BLOCK * PPT / 4) + tid;
    float4 v0 = mz4[base4];
    float4 v1 = mz4[base4 + BLOCK];

    // ---- phase 1: wave 0 computes transformed params + path checks ----
    if (tid < 64) {
        int t = tid;
        float p0 = pi_l[t];
        float p1 = pi_l[t + 64];
        float m = fmaxf(p0, p1);
        #pragma unroll
        for (int off = 1; off < 64; off <<= 1)
            m = fmaxf(m, __shfl_xor(m, off, 64));
        float e0 = expf(p0 - m);
        float e1 = expf(p1 - m);
        float s = e0 + e1;
        #pragma unroll
        for (int off = 1; off < 64; off <<= 1)
            s += __shfl_xor(s, off, 64);
        float inv_s = 1.0f / s;

        float lv0 = lv[t],      lv1 = lv[t + 64];
        float mu0 = mu[t],      mu1 = mu[t + 64];
        float A0 = -0.5f * expf(-lv0) * LOG2E;
        float A1 = -0.5f * expf(-lv1) * LOG2E;
        float lc0 = log2f(e0 * inv_s * INV_SQRT_2PI * expf(-0.5f * lv0));
        float lc1 = log2f(e1 * inv_s * INV_SQRT_2PI * expf(-0.5f * lv1));

        float del0 = fabsf(mu0 * 127.0f - (float)t);
        float del1 = fabsf(mu1 * 127.0f - (float)(t + 64));
        float d12_0 = sqrtf(fmaxf(lc0 + 12.0f, 0.0f) / (-A0)) * 127.0f;
        float d12_1 = sqrtf(fmaxf(lc1 + 12.0f, 0.0f) / (-A1)) * 127.0f;
        float d30_0 = sqrtf(fmaxf(lc0 + 30.0f, 0.0f) / (-A0)) * 127.0f;
        float d30_1 = sqrtf(fmaxf(lc1 + 30.0f, 0.0f) / (-A1)) * 127.0f;
        float r12 = fmaxf(del0 + d12_0, del1 + d12_1);
        float r30 = fmaxf(del0 + d30_0, del1 + d30_1);
        float amin = fminf(A0, A1),  amax = fmaxf(A0, A1);
        float lmin = fminf(lc0, lc1), lmax = fmaxf(lc0, lc1);
        #pragma unroll
        for (int off = 1; off < 64; off <<= 1) {
            r12 = fmaxf(r12, __shfl_xor(r12, off, 64));
            r30 = fmaxf(r30, __shfl_xor(r30, off, 64));
            amin = fminf(amin, __shfl_xor(amin, off, 64));
            amax = fmaxf(amax, __shfl_xor(amax, off, 64));
            lmin = fminf(lmin, __shfl_xor(lmin, off, 64));
            lmax = fmaxf(lmax, __shfl_xor(lmax, off, 64));
        }
        float sscl = sqrtf(-amax);           // uniform whenever win>=1 is taken
        sRaw[t]      = make_float4(mu0 * sscl, A0, lc0, mu0);
        sRaw[t + 64] = make_float4(mu1 * sscl, A1, lc1, mu1);
        if (t == 0) {
            sS = sscl;
            sLC = lmax;
            int w = 0;
            if (amin == amax) {
                if (r12 <= 3.0f)      w = (lmin == lmax) ? 3 : 2;
                else if (r30 <= 5.0f) w = 1;
            }
            sWin = w;
        }
    }
    __syncthreads();

    const int win = sWin;

    // ---- phase 2: build bank-replicated scaled-mu table (windowed paths only) ----
    if (win) {
        int r = tid & 31;
        int kb = (tid >> 5) << 4;            // 0,16,...,112
        #pragma unroll
        for (int i = 0; i < 16; i++) {
            int k = kb + i;
            smu[(k << 5) + r] = sRaw[k].x;   // bank = lane&31, 2-way alias free
        }
    }
    __syncthreads();

    float x[PPT];
    x[0] = v0.x; x[1] = v0.y; x[2] = v0.z; x[3] = v0.w;
    x[4] = v1.x; x[5] = v1.y; x[6] = v1.z; x[7] = v1.w;

    const float sscl = sS;
    const float lcu = sLC;
    const int lrep = tid & (REP - 1);
    const float* lcz = ((const float*)sRaw) + 2;

    float acc[PPT];
    if (win == 3) {
        eval_win<8, 3, true>(smu, lcz, lrep, sscl, lcu, x, acc);
    } else if (win == 2) {
        eval_win<8, 3, false>(smu, lcz, lrep, sscl, 0.0f, x, acc);
    } else if (win == 1) {
        eval_win<12, 5, false>(smu, lcz, lrep, sscl, 0.0f, x, acc);
    } else {
        #pragma unroll
        for (int p = 0; p < PPT; p++) acc[p] = 0.0f;
        #pragma unroll 2
        for (int k = 0; k < K_COMP; k++) {
            float4 raw = sRaw[k];            // broadcast (free)
            #pragma unroll
            for (int p = 0; p < PPT; p++) {
                float d = x[p] - raw.w;
                float t = __builtin_fmaf(d * raw.y, d, raw.z);
                acc[p] += __builtin_amdgcn_exp2f(t);
            }
        }
    }

    float4* out4 = (float4*)out;
    out4[base4] = make_float4(acc[0], acc[1], acc[2], acc[3]);
    out4[base4 + BLOCK] = make_float4(acc[4], acc[5], acc[6], acc[7]);
}

extern "C" void kernel_launch(void* const* d_in, const int* in_sizes, int n_in,
                              void* d_out, int out_size, void* d_ws, size_t ws_size,
                              hipStream_t stream) {
    const float* mz   = (const float*)d_in[0];
    const float* pi_l = (const float*)d_in[1];
    const float* mu   = (const float*)d_in[2];
    const float* lv   = (const float*)d_in[3];
    float* out = (float*)d_out;
    int n = in_sizes[0];                 // 4,194,304 (multiple of BLOCK*PPT)

    int grid = (n + BLOCK * PPT - 1) / (BLOCK * PPT);   // 2048
    gmm_fused<<<grid, BLOCK, 0, stream>>>(mz, pi_l, mu, lv, out, n);
}